// Round 4
// baseline (4877.918 us; speedup 1.0000x reference)
//
#include <hip/hip_runtime.h>
#include <hip/hip_bf16.h>
#include <stdint.h>

// Problem dims
#define BB 64
#define SS 512
#define EE 256
#define HH 512

typedef short s16x8 __attribute__((ext_vector_type(8)));
typedef float vf4 __attribute__((ext_vector_type(4)));

// Workspace byte offsets (256B aligned). Total = 206,080,512 B (~196.5 MiB)
#define OFF_WBT   0UL           // W bf16 transposed [2560][768]
#define OFF_EMB   3932160UL     // embedding bf16 [100][256]
#define OFF_WIT   3983360UL     // Wi bf16 transposed+padded [112][512]
#define OFF_DTT   4098048UL     // time_deltas transposed f32 [512][64]
#define OFF_FLAGS 4229120UL     // int flags, 131072 dwords (per (t,g,L), line-sharded)
#define OFF_CTL   4753408UL     // int ctl[128]: [0..63] wg->xcc+1, [64] arrive counter
#define OFF_HB    4753920UL     // h bf16 [8 groups][512 t][8 rows][512 cols]
#define OFF_ZXP   38308352UL    // zx bf16 frag-permuted [t][g][r][v][gate][32 lanes] uint2

// flag dword index: one 64B line per (group g, producer-wave L=r*4+v); t packed 16/line.
__device__ __forceinline__ int fidx(int t, int g, int L) {
  return (((t >> 4) * 256) + g * 32 + L) * 16 + (t & 15);
}

__device__ __forceinline__ unsigned short f2bf(float f) {
  unsigned u = __float_as_uint(f);
  u += 0x7fffu + ((u >> 16) & 1u);   // round-to-nearest-even
  return (unsigned short)(u >> 16);
}
__device__ __forceinline__ float bf2f(unsigned short h) {
  return __uint_as_float(((unsigned)h) << 16);
}
__device__ __forceinline__ float sigmoidf_(float x) { return 1.f / (1.f + __expf(-x)); }
__device__ __forceinline__ float softplusf_(float x) {
  return fmaxf(x, 0.f) + log1pf(__expf(-fabsf(x)));
}
__device__ __forceinline__ float tanhf_(float x) {   // overflow-safe
  float e = __expf(2.f * x);
  return 1.f - 2.f / (e + 1.f);
}

// ---------------- init: dtype conversions / transposes / flag+ctl zeroing ----------------
__global__ void init_kernel(const float* __restrict__ W, const float* __restrict__ emb,
                            const float* __restrict__ Wi, const float* __restrict__ td,
                            unsigned short* __restrict__ WbT, unsigned short* __restrict__ embB,
                            unsigned short* __restrict__ WiT, float* __restrict__ dtT,
                            int* __restrict__ flags) {
  unsigned i = blockIdx.x * 256u + threadIdx.x;
  if (i < 1966080u) {               // WbT[c][k] = bf16(W[k][c])
    unsigned c = i / 768u, k = i % 768u;
    WbT[i] = f2bf(W[(size_t)k * 2560u + c]);
    return;
  }
  i -= 1966080u;
  if (i < 25600u) { embB[i] = f2bf(emb[i]); return; }
  i -= 25600u;
  if (i < 57344u) {                 // WiT[c][k] = bf16(Wi[k][c]), pad c=100..111 with 0
    unsigned c = i / 512u, k = i % 512u;
    WiT[i] = f2bf(c < 100u ? Wi[(size_t)k * 100u + c] : 0.f);
    return;
  }
  i -= 57344u;
  if (i < 32768u) {                 // dtT[t][b] = td[b][t]
    unsigned t = i / 64u, b = i % 64u;
    dtT[i] = td[(size_t)b * 512u + t];
    return;
  }
  i -= 32768u;
  if (i < 131200u) { flags[i] = 0; return; }   // flags (131072) + ctl (128), adjacent
}

// ---------------- zx = gather(embedding) @ W_x + b, stored in per-(g,r,v,gate) frag layout ----
__global__ __launch_bounds__(256, 2)
void zx_kernel(const int* __restrict__ evt, const unsigned short* __restrict__ embB,
               const unsigned short* __restrict__ WbT, const float* __restrict__ bias,
               unsigned short* __restrict__ zxp) {
  const int t = blockIdx.y;
  const int tid = threadIdx.x;
  const int v = tid >> 6, lane = tid & 63;
  const int m = lane & 15, quad = lane >> 4;
  const int cbase = blockIdx.x * 256 + v * 64;  // wave's 64 output cols (4 frags)

  s16x8 Breg[8][4];
#pragma unroll
  for (int cf = 0; cf < 4; ++cf) {
    const unsigned short* bp = WbT + (size_t)(cbase + cf * 16 + m) * 768 + quad * 8;
#pragma unroll
    for (int ch = 0; ch < 8; ++ch) Breg[ch][cf] = *(const s16x8*)(bp + ch * 32);
  }
  int ev[4];
#pragma unroll
  for (int rt = 0; rt < 4; ++rt) ev[rt] = evt[(size_t)(rt * 16 + m) * 512 + t];

  vf4 acc[4][4];
#pragma unroll
  for (int cf = 0; cf < 4; ++cf) {
    float bbv = bias[cbase + cf * 16 + m];
#pragma unroll
    for (int rt = 0; rt < 4; ++rt) acc[rt][cf] = (vf4){bbv, bbv, bbv, bbv};
  }
#pragma unroll
  for (int ch = 0; ch < 8; ++ch) {
#pragma unroll
    for (int rt = 0; rt < 4; ++rt) {
      s16x8 a = *(const s16x8*)(embB + (size_t)ev[rt] * 256 + ch * 32 + quad * 8);
#pragma unroll
      for (int cf = 0; cf < 4; ++cf)
        acc[rt][cf] = __builtin_amdgcn_mfma_f32_16x16x32_bf16(a, Breg[ch][cf], acc[rt][cf], 0, 0, 0);
    }
  }
  // Store: batch row b = rt*16+quad*4+rr -> group g=b>>3, local row b&7.
#pragma unroll
  for (int cf = 0; cf < 4; ++cf) {
    int col0 = cbase + cf * 16;
    int gate = col0 >> 9;
    int hcol = col0 & 511;
    int rr_ = hcol >> 6;
    int vv = (hcol >> 4) & 3;
#pragma unroll
    for (int rt = 0; rt < 4; ++rt) {
      int gg = rt * 2 + (quad >> 1);
      unsigned h0 = f2bf(acc[rt][cf][0]);
      unsigned h1 = f2bf(acc[rt][cf][1]);
      unsigned h2 = f2bf(acc[rt][cf][2]);
      unsigned h3 = f2bf(acc[rt][cf][3]);
      uint2 val;
      val.x = h0 | (h1 << 16);
      val.y = h2 | (h3 << 16);
      ((uint2*)zxp)[(((((size_t)t * 8 + gg) * 8 + rr_) * 4 + vv) * 5 + gate) * 32
                    + (quad & 1) * 16 + m] = val;
    }
  }
}

// ---------------- persistent scan: 8 XCD-local groups x 8 WGs, wave-level flag sync ----------
// Group g (= blockIdx%8) owns batch rows [8g,8g+8). WG rank r (= blockIdx/8) owns h-cols
// [64r,64r+64); wave v owns h-cols [64r+16v,+16) x 5 gates (320 VGPRs of B-frags).
// Fast path (all 8 WGs verified on one XCC): flag sync via WORKGROUP-scope atomic RMWs --
// RMWs always execute at the XCD's TCC/L2 (L1 cannot serve atomics), so producer/consumer
// meet at the local L2 (~300cyc RT) instead of the Infinity Fabric coherence point.
// Poll adds 0x10000 (non-idempotent: InstCombine can't demote it to a cacheable load);
// flag truth value = low 16 bits. Fallback: round-2 agent-scope protocol.
__global__ __launch_bounds__(256, 1)
void scan_kernel(const unsigned short* __restrict__ WbT,
                 const unsigned short* __restrict__ zxp,
                 const float* __restrict__ dtT,
                 unsigned short* __restrict__ hb,
                 int* __restrict__ flags, int* __restrict__ ctl,
                 float* __restrict__ out_h, float* __restrict__ out_d) {
  const int wg = blockIdx.x;
  const int g = wg & 7, r = wg >> 3;
  const int tid = threadIdx.x;
  const int v = tid >> 6, lane = tid & 63;
  const int m = lane & 15, quad = lane >> 4;
  const int qh = quad & 1;
  const int c0 = r * 64 + v * 16;
  const int col = c0 + m;

  // --- one-time placement rendezvous: group is "local" iff all 8 WGs share an XCC ---
  __shared__ int s_loc;
  if (tid == 0) {
    unsigned xcc = __builtin_amdgcn_s_getreg(63508) & 0xfu;  // hwreg(HW_REG_XCC_ID=20,0,32)
    __hip_atomic_store(&ctl[wg], (int)(xcc + 1u), __ATOMIC_RELAXED, __HIP_MEMORY_SCOPE_AGENT);
    __hip_atomic_fetch_add(&ctl[64], 1, __ATOMIC_RELEASE, __HIP_MEMORY_SCOPE_AGENT);
    while (__hip_atomic_load(&ctl[64], __ATOMIC_ACQUIRE, __HIP_MEMORY_SCOPE_AGENT) < 64)
      __builtin_amdgcn_s_sleep(1);
    int x0 = __hip_atomic_load(&ctl[g], __ATOMIC_RELAXED, __HIP_MEMORY_SCOPE_AGENT);
    int lc = (x0 != 0);
    for (int j = 1; j < 8; ++j)
      lc &= (__hip_atomic_load(&ctl[g + 8 * j], __ATOMIC_RELAXED, __HIP_MEMORY_SCOPE_AGENT) == x0);
    s_loc = lc;
  }
  __syncthreads();
  const bool loc = (s_loc != 0);

  // W_h slice in registers: Breg[ch][gate], k = 256 + ch*32 + quad*8 + j, col = gate*512+c0+m
  s16x8 Breg[16][5];
#pragma unroll
  for (int g5 = 0; g5 < 5; ++g5) {
    const unsigned short* bp = WbT + (size_t)(g5 * 512 + c0 + m) * 768 + 256 + quad * 8;
#pragma unroll
    for (int ch = 0; ch < 16; ++ch) Breg[ch][g5] = *(const s16x8*)(bp + ch * 32);
  }

  vf4 cst = (vf4){0.f, 0.f, 0.f, 0.f};

  for (int t = 0; t < 512; ++t) {
    // acc init from zx (independent of recurrence; only quads 0,1 hold valid rows)
    vf4 acc[5];
    if (lane < 32) {
#pragma unroll
      for (int g5 = 0; g5 < 5; ++g5) {
        uint2 zv = ((const uint2*)zxp)[(((((size_t)t * 8 + g) * 8 + r) * 4 + v) * 5 + g5) * 32 + lane];
        acc[g5][0] = bf2f((unsigned short)(zv.x & 0xffffu));
        acc[g5][1] = bf2f((unsigned short)(zv.x >> 16));
        acc[g5][2] = bf2f((unsigned short)(zv.y & 0xffffu));
        acc[g5][3] = bf2f((unsigned short)(zv.y >> 16));
      }
    } else {
#pragma unroll
      for (int g5 = 0; g5 < 5; ++g5) acc[g5] = (vf4){0.f, 0.f, 0.f, 0.f};
    }
    vf4 dt4 = *(const vf4*)(dtT + t * 64 + g * 8 + qh * 4);

    if (t > 0) {
      const int tp = t - 1;
      if (lane < 32) {
        int* fp = flags + fidx(tp, g, lane);
        if (loc) {
          // TCC-executed RMW poll: immune to L1 caching, local-L2 latency.
          while ((__hip_atomic_fetch_add(fp, 0x10000, __ATOMIC_RELAXED,
                                         __HIP_MEMORY_SCOPE_WORKGROUP) & 0xffff) == 0) {}
        } else {
          while (__hip_atomic_load(fp, __ATOMIC_RELAXED, __HIP_MEMORY_SCOPE_AGENT) == 0)
            __builtin_amdgcn_s_sleep(1);
        }
      }
      __asm__ __volatile__("" ::: "memory");
      // A-frags from group h buffer (local-L2-resident on fast path): row m&7 (rows 8..15 dup)
      const unsigned short* hsrc = hb + (((size_t)g * 512 + tp) * 8 + (m & 7)) * 512 + quad * 8;
#pragma unroll
      for (int ch = 0; ch < 16; ++ch) {
        s16x8 a = *(const s16x8*)(hsrc + ch * 32);
#pragma unroll
        for (int g5 = 0; g5 < 5; ++g5)
          acc[g5] = __builtin_amdgcn_mfma_f32_16x16x32_bf16(a, Breg[ch][g5], acc[g5], 0, 0, 0);
      }
    }

    float hv[4], dv[4];
#pragma unroll
    for (int rr = 0; rr < 4; ++rr) {
      float i_ = sigmoidf_(acc[0][rr]);
      float f_ = sigmoidf_(acc[1][rr]);
      float o_ = sigmoidf_(acc[2][rr]);
      float g_ = tanhf_(acc[3][rr]);
      float dec = softplusf_(acc[4][rr]);
      float cn = f_ * cst[rr] + i_ * g_;
      float ct = cn * __expf(-dec * dt4[rr]);
      float h_ = o_ * tanhf_(ct);
      cst[rr] = ct;
      hv[rr] = h_; dv[rr] = dec;
    }
    // publish h: quads 0,1 hold the 8 valid rows (local row = quad*4+rr)
    if (quad < 2) {
#pragma unroll
      for (int rr = 0; rr < 4; ++rr) {
        unsigned short* hp = hb + (((size_t)g * 512 + t) * 8 + quad * 4 + rr) * 512 + col;
        if (loc) *(volatile unsigned short*)hp = f2bf(hv[rr]);   // write-through -> local L2
        else __hip_atomic_store(hp, f2bf(hv[rr]), __ATOMIC_RELAXED, __HIP_MEMORY_SCOPE_AGENT);
      }
    }
    __asm__ __volatile__("" ::: "memory");
    asm volatile("s_waitcnt vmcnt(0)" ::: "memory");   // h-stores committed before flag
    if (lane == 0) {
      int* fp = flags + fidx(t, g, r * 4 + v);
      if (loc) (void)__hip_atomic_exchange(fp, 1, __ATOMIC_RELAXED, __HIP_MEMORY_SCOPE_WORKGROUP);
      else __hip_atomic_store(fp, 1, __ATOMIC_RELAXED, __HIP_MEMORY_SCOPE_AGENT);
    }
    // off-critical-path fp32 outputs (drain overlapped with next step)
    if (quad < 2) {
#pragma unroll
      for (int rr = 0; rr < 4; ++rr) {
        int b_ = g * 8 + quad * 4 + rr;
        size_t oo = ((size_t)b_ * SS + t) * HH + col;
        out_h[oo] = hv[rr];
        out_d[oo] = dv[rr];
      }
    }
  }
}

// ---------------- base_intensities = softplus(h @ Wi + bi) ----------------
__global__ __launch_bounds__(256, 2)
void inten_kernel(const unsigned short* __restrict__ hb,
                  const unsigned short* __restrict__ WiT,
                  const float* __restrict__ bi,
                  float* __restrict__ out_i) {
  const int b = blockIdx.y;            // batch row
  const int t0 = blockIdx.x * 64;      // 64 timesteps per WG
  const int tid = threadIdx.x;
  const int v = tid >> 6, lane = tid & 63;
  const int m = lane & 15, quad = lane >> 4;
  const int trow = t0 + v * 16 + m;    // A row = timestep

  vf4 acc[7];
#pragma unroll
  for (int cf = 0; cf < 7; ++cf) {
    int c = cf * 16 + m;
    float bbv = (c < 100) ? bi[c] : 0.f;
    acc[cf] = (vf4){bbv, bbv, bbv, bbv};
  }
  const unsigned short* ha = hb + (((size_t)(b >> 3) * 512 + trow) * 8 + (b & 7)) * 512 + quad * 8;
#pragma unroll 4
  for (int ch = 0; ch < 16; ++ch) {
    s16x8 a = *(const s16x8*)(ha + ch * 32);
#pragma unroll
    for (int cf = 0; cf < 7; ++cf) {
      s16x8 bf = *(const s16x8*)(WiT + (size_t)(cf * 16 + m) * 512 + ch * 32 + quad * 8);
      acc[cf] = __builtin_amdgcn_mfma_f32_16x16x32_bf16(a, bf, acc[cf], 0, 0, 0);
    }
  }
#pragma unroll
  for (int cf = 0; cf < 7; ++cf) {
    int c = cf * 16 + m;
#pragma unroll
    for (int rr = 0; rr < 4; ++rr) {
      int tt = t0 + v * 16 + quad * 4 + rr;
      if (c < 100) out_i[((size_t)b * 512 + tt) * 100 + c] = softplusf_(acc[cf][rr]);
    }
  }
}

extern "C" void kernel_launch(void* const* d_in, const int* in_sizes, int n_in,
                              void* d_out, int out_size, void* d_ws, size_t ws_size,
                              hipStream_t stream) {
  (void)in_sizes; (void)n_in; (void)out_size; (void)ws_size;
  const int*   evt  = (const int*)d_in[0];
  const float* td   = (const float*)d_in[1];
  const float* emb  = (const float*)d_in[2];
  const float* W    = (const float*)d_in[3];
  const float* bias = (const float*)d_in[4];
  const float* Wi   = (const float*)d_in[5];
  const float* bi   = (const float*)d_in[6];

  char* ws = (char*)d_ws;
  unsigned short* WbT  = (unsigned short*)(ws + OFF_WBT);
  unsigned short* embB = (unsigned short*)(ws + OFF_EMB);
  unsigned short* WiT  = (unsigned short*)(ws + OFF_WIT);
  float*          dtT  = (float*)(ws + OFF_DTT);
  int*            flags= (int*)(ws + OFF_FLAGS);
  int*            ctl  = (int*)(ws + OFF_CTL);
  unsigned short* hb   = (unsigned short*)(ws + OFF_HB);
  unsigned short* zxp  = (unsigned short*)(ws + OFF_ZXP);

  float* out_h = (float*)d_out;
  float* out_d = out_h + (size_t)BB * SS * HH;
  float* out_i = out_d + (size_t)BB * SS * HH;

  init_kernel<<<8645, 256, 0, stream>>>(W, emb, Wi, td, WbT, embB, WiT, dtT, flags);
  zx_kernel<<<dim3(10, 512), 256, 0, stream>>>(evt, embB, WbT, bias, zxp);
  scan_kernel<<<64, 256, 0, stream>>>(WbT, zxp, dtT, hb, flags, ctl, out_h, out_d);
  inten_kernel<<<dim3(8, 64), 256, 0, stream>>>(hb, WiT, bi, out_i);
}